// Round 8
// baseline (1460.484 us; speedup 1.0000x reference)
//
#include <hip/hip_runtime.h>
#include <hip/hip_bf16.h>
#include <math.h>

static constexpr int Bn = 2, Ln = 16, Tn = 2048, Dn = 1024, Un = 64;
static constexpr float SCALE_ATTN = 0.14232867951f; // (0.1*ln(4)+1)/sqrt(64)

// YaRN NTK-by-parts inverse frequency. HEAD_DIM=64 (half=32), theta=1e4,
// scale=4 => low=floor(8.064)=8, high=min(ceil(20.106),31)=21, denom=13.
__device__ __forceinline__ float inv_freq_of(int d) {
    float p = powf(10000.0f, (float)d * (1.0f / 32.0f));
    float extra = 1.0f / p;
    float inter = 0.25f / p;
    float ramp = ((float)d - 8.0f) * (1.0f / 13.0f);
    ramp = fminf(fmaxf(ramp, 0.0f), 1.0f);
    return inter * ramp + extra * (1.0f - ramp);
}

// ---------------------------------------------------------------------------
// Kernel A: per-head QKV projection (64 rows x 64 cols per block, K=1024)
// fused with YaRN RoPE epilogue. All fp32. Thread owns 4 rows x cols
// {2cg,2cg+1,2cg+32,2cg+33} so the rotate-half pair (d, d+32) is thread-local.
// ---------------------------------------------------------------------------
__global__ __launch_bounds__(256) void qkv_rope(
    const float* __restrict__ emb, const int* __restrict__ pos,
    const float* __restrict__ qp, const float* __restrict__ kp,
    const float* __restrict__ vp,
    float* __restrict__ Qw, float* __restrict__ Kw, float* __restrict__ Vw)
{
    __shared__ float As[64][36];     // 64x32 K-slab of embeddings
    __shared__ float Wq[32][64];
    __shared__ float Wk[32][64];
    __shared__ float Wv[32][64];

    const int z = blockIdx.y;            // b*L + l
    const int l = z & (Ln - 1);
    const int row0 = blockIdx.x * 64;
    const int tid = (int)threadIdx.x;
    const int rg = tid >> 4;             // rows 4rg..4rg+3
    const int cg = tid & 15;             // cols 2cg,2cg+1,2cg+32,2cg+33

    const float* embB = emb + ((size_t)z * Tn + row0) * Dn;
    const float* qpB = qp + (size_t)l * Dn * Un;
    const float* kpB = kp + (size_t)l * Dn * Un;
    const float* vpB = vp + (size_t)l * Dn * Un;

    float4 aq[4], ak[4], av[4];
    #pragma unroll
    for (int i = 0; i < 4; ++i) {
        aq[i] = make_float4(0.f, 0.f, 0.f, 0.f);
        ak[i] = make_float4(0.f, 0.f, 0.f, 0.f);
        av[i] = make_float4(0.f, 0.f, 0.f, 0.f);
    }

    for (int k0 = 0; k0 < Dn; k0 += 32) {
        #pragma unroll
        for (int it = 0; it < 2; ++it) {
            int fi = tid + 256 * it;
            int r = fi >> 3, c4 = (fi & 7) << 2;
            *(float4*)&As[r][c4] = *(const float4*)(embB + (size_t)r * Dn + k0 + c4);
        }
        #pragma unroll
        for (int it = 0; it < 2; ++it) {
            int fi = tid + 256 * it;
            int kr = fi >> 4, c4 = (fi & 15) << 2;
            size_t off = (size_t)(k0 + kr) * Un + c4;
            *(float4*)&Wq[kr][c4] = *(const float4*)(qpB + off);
            *(float4*)&Wk[kr][c4] = *(const float4*)(kpB + off);
            *(float4*)&Wv[kr][c4] = *(const float4*)(vpB + off);
        }
        __syncthreads();
        #pragma unroll 8
        for (int kk = 0; kk < 32; ++kk) {
            float a[4];
            #pragma unroll
            for (int i = 0; i < 4; ++i) a[i] = As[4 * rg + i][kk];
            float2 qlo = *(float2*)&Wq[kk][2 * cg];
            float2 qhi = *(float2*)&Wq[kk][2 * cg + 32];
            float2 klo = *(float2*)&Wk[kk][2 * cg];
            float2 khi = *(float2*)&Wk[kk][2 * cg + 32];
            float2 vlo = *(float2*)&Wv[kk][2 * cg];
            float2 vhi = *(float2*)&Wv[kk][2 * cg + 32];
            #pragma unroll
            for (int i = 0; i < 4; ++i) {
                aq[i].x += a[i] * qlo.x; aq[i].y += a[i] * qlo.y;
                aq[i].z += a[i] * qhi.x; aq[i].w += a[i] * qhi.y;
                ak[i].x += a[i] * klo.x; ak[i].y += a[i] * klo.y;
                ak[i].z += a[i] * khi.x; ak[i].w += a[i] * khi.y;
                av[i].x += a[i] * vlo.x; av[i].y += a[i] * vlo.y;
                av[i].z += a[i] * vhi.x; av[i].w += a[i] * vhi.y;
            }
        }
        __syncthreads();
    }

    // RoPE epilogue: cols (d0, d0+1, d0+32, d0+33); pair (d, d+32) shares angle.
    const int d0 = 2 * cg;
    const float if0 = inv_freq_of(d0);
    const float if1 = inv_freq_of(d0 + 1);
    #pragma unroll
    for (int i = 0; i < 4; ++i) {
        int row = row0 + 4 * rg + i;
        float fp = (float)pos[(size_t)z * Tn + row];
        float s0, c0, s1, c1;
        sincosf(fp * if0, &s0, &c0);
        sincosf(fp * if1, &s1, &c1);
        float4 q = aq[i], k = ak[i], v = av[i];
        float qx = q.x * c0 - q.z * s0, qz = q.z * c0 + q.x * s0;
        float qy = q.y * c1 - q.w * s1, qw = q.w * c1 + q.y * s1;
        float kx = k.x * c0 - k.z * s0, kz = k.z * c0 + k.x * s0;
        float ky = k.y * c1 - k.w * s1, kw = k.w * c1 + k.y * s1;
        size_t base = ((size_t)z * Tn + row) * Un;
        *(float2*)&Qw[base + d0]      = make_float2(qx, qy);
        *(float2*)&Qw[base + d0 + 32] = make_float2(qz, qw);
        *(float2*)&Kw[base + d0]      = make_float2(kx, ky);
        *(float2*)&Kw[base + d0 + 32] = make_float2(kz, kw);
        *(float2*)&Vw[base + d0]      = make_float2(v.x, v.y);
        *(float2*)&Vw[base + d0 + 32] = make_float2(v.z, v.w);
    }
}

// ---------------------------------------------------------------------------
// Kernel B: fp32 flash attention per (b,l). 64 query rows per block, KV tiles
// of 64, online softmax. Mask = activeQ & activeK & causal; inactive query
// rows produce exact 0 (matches reference's attended * active_mask).
// Mask element width (1-byte bool vs int32) detected on-device:
// int32 0/1 values have bytes 1..3 of every word == 0; random u8 bools don't.
// ---------------------------------------------------------------------------
__global__ __launch_bounds__(256) void flash_attn(
    const float* __restrict__ Qw, const float* __restrict__ Kw,
    const float* __restrict__ Vw, const unsigned char* __restrict__ act,
    float* __restrict__ Att)
{
    __shared__ float Qs[64][68];
    __shared__ float Ks[64][68];
    __shared__ float Vs[64][68];
    __shared__ float Ps[64][68];
    __shared__ unsigned char actK[64];
    __shared__ int u8flag;

    const int z = blockIdx.y;
    const int rt = (int)gridDim.x - 1 - (int)blockIdx.x;  // longest-first
    const int row0 = rt * 64;
    const int tid = (int)threadIdx.x;
    const int rg = tid >> 4;   // rows 4rg..4rg+3
    const int cg = tid & 15;   // key cols / out dims 4cg..4cg+3

    // ---- mask dtype detection (first 1024 bytes; valid for either layout) --
    if (tid == 0) u8flag = 0;
    __syncthreads();
    {
        int b = tid * 4;
        int nz = (int)act[b + 1] | (int)act[b + 2] | (int)act[b + 3];
        if (nz) atomicOr(&u8flag, 1);
    }

    const float* qB = Qw + ((size_t)z * Tn + row0) * Un;
    #pragma unroll
    for (int it = 0; it < 4; ++it) {
        int fi = tid + 256 * it;
        int r = fi >> 4, c4 = (fi & 15) << 2;
        *(float4*)&Qs[r][c4] = *(const float4*)(qB + (size_t)r * Un + c4);
    }
    __syncthreads();
    const bool isU8 = (u8flag != 0);
    const int* act32 = (const int*)act;

    bool aqv[4];
    float m[4], lsum[4];
    float4 o[4];
    #pragma unroll
    for (int i = 0; i < 4; ++i) {
        size_t mi = (size_t)z * Tn + row0 + 4 * rg + i;
        aqv[i] = isU8 ? (act[mi] != 0) : (act32[mi] != 0);
        m[i] = -INFINITY; lsum[i] = 0.f;
        o[i] = make_float4(0.f, 0.f, 0.f, 0.f);
    }

    for (int kt = 0; kt <= rt; ++kt) {
        const int j0 = kt * 64;
        __syncthreads();   // previous tile's readers done before overwrite
        #pragma unroll
        for (int it = 0; it < 4; ++it) {
            int fi = tid + 256 * it;
            int r = fi >> 4, c4 = (fi & 15) << 2;
            size_t g = ((size_t)z * Tn + j0 + r) * Un + c4;
            *(float4*)&Ks[r][c4] = *(const float4*)(Kw + g);
            *(float4*)&Vs[r][c4] = *(const float4*)(Vw + g);
        }
        if (tid < 64) {
            size_t mi = (size_t)z * Tn + j0 + tid;
            actK[tid] = isU8 ? (act[mi] != 0) : (unsigned char)(act32[mi] != 0);
        }
        __syncthreads();

        // S = Q K^T for 4x4 sub-tile
        float4 s[4];
        #pragma unroll
        for (int i = 0; i < 4; ++i) s[i] = make_float4(0.f, 0.f, 0.f, 0.f);
        #pragma unroll 4
        for (int k4 = 0; k4 < 16; ++k4) {
            float4 qv[4], kv[4];
            #pragma unroll
            for (int i = 0; i < 4; ++i) qv[i] = *(float4*)&Qs[4 * rg + i][k4 << 2];
            #pragma unroll
            for (int j = 0; j < 4; ++j) kv[j] = *(float4*)&Ks[4 * cg + j][k4 << 2];
            #pragma unroll
            for (int i = 0; i < 4; ++i) {
                s[i].x += qv[i].x * kv[0].x + qv[i].y * kv[0].y + qv[i].z * kv[0].z + qv[i].w * kv[0].w;
                s[i].y += qv[i].x * kv[1].x + qv[i].y * kv[1].y + qv[i].z * kv[1].z + qv[i].w * kv[1].w;
                s[i].z += qv[i].x * kv[2].x + qv[i].y * kv[2].y + qv[i].z * kv[2].z + qv[i].w * kv[2].w;
                s[i].w += qv[i].x * kv[3].x + qv[i].y * kv[3].y + qv[i].z * kv[3].z + qv[i].w * kv[3].w;
            }
        }

        const bool av0 = actK[4 * cg + 0] != 0;
        const bool av1 = actK[4 * cg + 1] != 0;
        const bool av2 = actK[4 * cg + 2] != 0;
        const bool av3 = actK[4 * cg + 3] != 0;
        #pragma unroll
        for (int i = 0; i < 4; ++i) {
            const int rowg = row0 + 4 * rg + i;
            float sx = (aqv[i] && av0 && (j0 + 4 * cg + 0) <= rowg) ? s[i].x * SCALE_ATTN : -INFINITY;
            float sy = (aqv[i] && av1 && (j0 + 4 * cg + 1) <= rowg) ? s[i].y * SCALE_ATTN : -INFINITY;
            float sz = (aqv[i] && av2 && (j0 + 4 * cg + 2) <= rowg) ? s[i].z * SCALE_ATTN : -INFINITY;
            float sw = (aqv[i] && av3 && (j0 + 4 * cg + 3) <= rowg) ? s[i].w * SCALE_ATTN : -INFINITY;
            float mt = fmaxf(fmaxf(sx, sy), fmaxf(sz, sw));
            mt = fmaxf(mt, __shfl_xor(mt, 1));
            mt = fmaxf(mt, __shfl_xor(mt, 2));
            mt = fmaxf(mt, __shfl_xor(mt, 4));
            mt = fmaxf(mt, __shfl_xor(mt, 8));
            float mnew = fmaxf(m[i], mt);
            float4 p; float corr;
            if (mnew == -INFINITY) {        // row has no valid key yet
                p = make_float4(0.f, 0.f, 0.f, 0.f); corr = 1.f;
            } else {
                corr = expf(m[i] - mnew);   // m[i]=-inf -> 0, correct
                p.x = expf(sx - mnew); p.y = expf(sy - mnew);
                p.z = expf(sz - mnew); p.w = expf(sw - mnew);
            }
            float ps = p.x + p.y + p.z + p.w;
            ps += __shfl_xor(ps, 1);
            ps += __shfl_xor(ps, 2);
            ps += __shfl_xor(ps, 4);
            ps += __shfl_xor(ps, 8);
            m[i] = mnew;
            lsum[i] = lsum[i] * corr + ps;
            o[i].x *= corr; o[i].y *= corr; o[i].z *= corr; o[i].w *= corr;
            *(float4*)&Ps[4 * rg + i][cg << 2] = p;
        }
        __syncthreads();

        // O += P V  (dims 4cg..4cg+3 per thread)
        #pragma unroll 4
        for (int k4 = 0; k4 < 16; ++k4) {
            float4 pv[4], vv[4];
            #pragma unroll
            for (int i = 0; i < 4; ++i) pv[i] = *(float4*)&Ps[4 * rg + i][k4 << 2];
            #pragma unroll
            for (int mm = 0; mm < 4; ++mm) vv[mm] = *(float4*)&Vs[(k4 << 2) + mm][cg << 2];
            #pragma unroll
            for (int i = 0; i < 4; ++i) {
                o[i].x += pv[i].x * vv[0].x + pv[i].y * vv[1].x + pv[i].z * vv[2].x + pv[i].w * vv[3].x;
                o[i].y += pv[i].x * vv[0].y + pv[i].y * vv[1].y + pv[i].z * vv[2].y + pv[i].w * vv[3].y;
                o[i].z += pv[i].x * vv[0].z + pv[i].y * vv[1].z + pv[i].z * vv[2].z + pv[i].w * vv[3].z;
                o[i].w += pv[i].x * vv[0].w + pv[i].y * vv[1].w + pv[i].z * vv[2].w + pv[i].w * vv[3].w;
            }
        }
    }

    #pragma unroll
    for (int i = 0; i < 4; ++i) {
        float inv = (aqv[i] && lsum[i] > 0.f) ? 1.0f / lsum[i] : 0.f;
        float4 r = make_float4(o[i].x * inv, o[i].y * inv, o[i].z * inv, o[i].w * inv);
        *(float4*)&Att[((size_t)z * Tn + row0 + 4 * rg + i) * Un + (cg << 2)] = r;
    }
}

// ---------------------------------------------------------------------------
// Kernel C: out = attended (B*L*T x 64) @ o_proj[l] (64 x 1024), FP32 output
// (reference output dtype is float32 -> d_out is float*).
// Block computes 64 rows x 128 cols, K=64 single shot.
// ---------------------------------------------------------------------------
__global__ __launch_bounds__(256) void oproj(
    const float* __restrict__ Att, const float* __restrict__ op,
    float* __restrict__ out)
{
    __shared__ float As[64][68];
    __shared__ float Ws[64][132];
    const int row0 = blockIdx.y * 64;    // flat over B*L*T (64 rows share one l)
    const int c0 = blockIdx.x * 128;
    const int l = (row0 / Tn) & (Ln - 1);
    const int tid = (int)threadIdx.x;
    const int rg = tid >> 4;
    const int cg = tid & 15;

    #pragma unroll
    for (int it = 0; it < 4; ++it) {
        int fi = tid + 256 * it;
        int r = fi >> 4, c4 = (fi & 15) << 2;
        *(float4*)&As[r][c4] = *(const float4*)(Att + (size_t)(row0 + r) * Un + c4);
    }
    const float* opB = op + (size_t)l * Un * Dn + c0;
    #pragma unroll
    for (int it = 0; it < 8; ++it) {
        int fi = tid + 256 * it;
        int r = fi >> 5, c4 = (fi & 31) << 2;
        *(float4*)&Ws[r][c4] = *(const float4*)(opB + (size_t)r * Dn + c4);
    }
    __syncthreads();

    float4 accA[4], accB[4];
    #pragma unroll
    for (int i = 0; i < 4; ++i) {
        accA[i] = make_float4(0.f, 0.f, 0.f, 0.f);
        accB[i] = make_float4(0.f, 0.f, 0.f, 0.f);
    }
    #pragma unroll 8
    for (int k = 0; k < 64; ++k) {
        float a[4];
        #pragma unroll
        for (int i = 0; i < 4; ++i) a[i] = As[4 * rg + i][k];
        float4 wA = *(float4*)&Ws[k][8 * cg];
        float4 wB = *(float4*)&Ws[k][8 * cg + 4];
        #pragma unroll
        for (int i = 0; i < 4; ++i) {
            accA[i].x += a[i] * wA.x; accA[i].y += a[i] * wA.y;
            accA[i].z += a[i] * wA.z; accA[i].w += a[i] * wA.w;
            accB[i].x += a[i] * wB.x; accB[i].y += a[i] * wB.y;
            accB[i].z += a[i] * wB.z; accB[i].w += a[i] * wB.w;
        }
    }
    #pragma unroll
    for (int i = 0; i < 4; ++i) {
        size_t base = (size_t)(row0 + 4 * rg + i) * Dn + c0 + 8 * cg;
        *(float4*)&out[base] = accA[i];
        *(float4*)&out[base + 4] = accB[i];
    }
}

extern "C" void kernel_launch(void* const* d_in, const int* in_sizes, int n_in,
                              void* d_out, int out_size, void* d_ws, size_t ws_size,
                              hipStream_t stream) {
    const float* emb = (const float*)d_in[0];
    const int* pos = (const int*)d_in[1];
    const unsigned char* act = (const unsigned char*)d_in[2]; // bool OR int32 — detected on device
    const float* qp = (const float*)d_in[3];
    const float* kp = (const float*)d_in[4];
    const float* vp = (const float*)d_in[5];
    const float* op = (const float*)d_in[6];
    float* out = (float*)d_out;

    float* ws = (float*)d_ws;
    const size_t SLAB = (size_t)Bn * Ln * Tn * Un;  // 4,194,304 floats (16 MB)
    float* Qw = ws;
    float* Kw = ws + SLAB;
    float* Vw = ws + 2 * SLAB;
    float* At = ws + 3 * SLAB;   // total 64 MB of d_ws used

    dim3 blk(256);
    qkv_rope<<<dim3(Tn / 64, Bn * Ln), blk, 0, stream>>>(emb, pos, qp, kp, vp, Qw, Kw, Vw);
    flash_attn<<<dim3(Tn / 64, Bn * Ln), blk, 0, stream>>>(Qw, Kw, Vw, act, At);
    oproj<<<dim3(Dn / 128, (Bn * Ln * Tn) / 64), blk, 0, stream>>>(At, op, out);
}

// Round 11
// 766.667 us; speedup vs baseline: 1.9050x; 1.9050x over previous
//
#include <hip/hip_runtime.h>
#include <hip/hip_bf16.h>
#include <math.h>

typedef __attribute__((ext_vector_type(8))) short bf16x8;
typedef __attribute__((ext_vector_type(4))) float f32x4;

static constexpr int Bn = 2, Ln = 16, Tn = 2048, Dn = 1024, Un = 64;
static constexpr float SCALE_ATTN = 0.14232867951f; // (0.1*ln(4)+1)/sqrt(64)
static constexpr int VTS = 2080;                    // V^T ws row stride (elems)

__device__ __forceinline__ unsigned short f2bf(float x) {
    __hip_bfloat16 h = __float2bfloat16(x);
    return *reinterpret_cast<unsigned short*>(&h);
}
__device__ __forceinline__ unsigned int pk2(float a, float b) {
    return (unsigned int)f2bf(a) | ((unsigned int)f2bf(b) << 16);
}
// YaRN: low=8, high=21, denom=13 (validated by R8 pass)
__device__ __forceinline__ float inv_freq_of(int d) {
    float p = powf(10000.0f, (float)d * (1.0f / 32.0f));
    float ramp = fminf(fmaxf(((float)d - 8.0f) * (1.0f / 13.0f), 0.0f), 1.0f);
    return (0.25f / p) * ramp + (1.0f / p) * (1.0f - ramp);
}

// ---------------------------------------------------------------------------
// prep_w: fp32 weights -> bf16, transposed for contiguous MFMA B-fragments.
// qt/kt/vt: [l][u=64][k=1024]; ot: [l][d=1024][u=64]. 64x64 tile per block.
// ---------------------------------------------------------------------------
__global__ __launch_bounds__(256) void prep_w(
    const float* __restrict__ qp, const float* __restrict__ kp,
    const float* __restrict__ vp, const float* __restrict__ op,
    unsigned short* __restrict__ qt, unsigned short* __restrict__ kt,
    unsigned short* __restrict__ vt, unsigned short* __restrict__ ot)
{
    __shared__ unsigned short T[64][72];
    const int m = blockIdx.z, l = blockIdx.y, x = blockIdx.x;
    const int tid = (int)threadIdx.x;
    const float* sb = (m == 0 ? qp : m == 1 ? kp : m == 2 ? vp : op) + (size_t)l * 65536;
    unsigned short* db = (m == 0 ? qt : m == 1 ? kt : m == 2 ? vt : ot) + (size_t)l * 65536;
    #pragma unroll
    for (int p = 0; p < 4; ++p) {
        int r = (tid >> 4) + 16 * p, c4 = (tid & 15) * 4;
        size_t s = (m < 3) ? ((size_t)(64 * x + r) * 64 + c4)      // rows=k, cols=u
                           : ((size_t)r * 1024 + 64 * x + c4);     // rows=u, cols=d
        float4 v = *(const float4*)(sb + s);
        T[r][c4 + 0] = f2bf(v.x); T[r][c4 + 1] = f2bf(v.y);
        T[r][c4 + 2] = f2bf(v.z); T[r][c4 + 3] = f2bf(v.w);
    }
    __syncthreads();
    #pragma unroll
    for (int p = 0; p < 2; ++p) {
        int task = tid + 256 * p;
        int c = task >> 3, g = task & 7;
        uint4 wv; unsigned short* wp = (unsigned short*)&wv;
        #pragma unroll
        for (int j = 0; j < 8; ++j) wp[j] = T[8 * g + j][c];
        size_t d = (m < 3) ? ((size_t)c * 1024 + 64 * x + 8 * g)   // qt[u=c][k]
                           : ((size_t)(64 * x + c) * 64 + 8 * g);  // ot[d][u]
        *(uint4*)(db + d) = wv;
    }
}

// ---------------------------------------------------------------------------
// qkv_rope (MFMA): per block one (b,l), 64 rows x 192 cols, K=1024.
// A staged bf16 in LDS; B read direct from L2-resident transposed bf16 ws.
// RoPE on fp32 accumulators; LDS repack -> coalesced stores; V stored [d][t].
// ---------------------------------------------------------------------------
__global__ __launch_bounds__(256) void qkv_rope(
    const float* __restrict__ emb, const int* __restrict__ pos,
    const unsigned short* __restrict__ qt, const unsigned short* __restrict__ kt,
    const unsigned short* __restrict__ vt,
    unsigned short* __restrict__ Qw, unsigned short* __restrict__ Kw,
    unsigned short* __restrict__ Vt)
{
    __shared__ unsigned short A_lds[64][40];
    __shared__ unsigned short O_lds[64][200];
    const int z = blockIdx.y, l = z & 15, row0 = blockIdx.x * 64;
    const int tid = (int)threadIdx.x;
    const int w = tid >> 6, lane = tid & 63, hi = lane >> 4, lo = lane & 15;

    f32x4 acc[12];
    #pragma unroll
    for (int i = 0; i < 12; ++i) acc[i] = (f32x4){0.f, 0.f, 0.f, 0.f};

    const float* embB = emb + ((size_t)z * Tn + row0) * Dn;
    const unsigned short* wq = qt + (size_t)l * 65536;
    const unsigned short* wk = kt + (size_t)l * 65536;
    const unsigned short* wv = vt + (size_t)l * 65536;

    for (int k0 = 0; k0 < Dn; k0 += 32) {
        {   // stage A tile 64x32 -> bf16
            int r = tid >> 2, c8 = (tid & 3) * 8;
            const float* s = embB + (size_t)r * Dn + k0 + c8;
            float4 v0 = *(const float4*)s, v1 = *(const float4*)(s + 4);
            uint4 u = {pk2(v0.x, v0.y), pk2(v0.z, v0.w), pk2(v1.x, v1.y), pk2(v1.z, v1.w)};
            *(uint4*)&A_lds[r][c8] = u;
        }
        __syncthreads();
        bf16x8 a = *(const bf16x8*)&A_lds[16 * w + lo][8 * hi];
        #pragma unroll
        for (int n = 0; n < 12; ++n) {
            const unsigned short* wb = (n < 4) ? wq : (n < 8) ? wk : wv;
            const unsigned short* bp = wb + (size_t)(16 * (n & 3) + lo) * 1024 + k0 + 8 * hi;
            bf16x8 b = *(const bf16x8*)bp;
            acc[n] = __builtin_amdgcn_mfma_f32_16x16x32_bf16(a, b, acc[n], 0, 0, 0);
        }
        __syncthreads();
    }

    // RoPE epilogue -> O_lds (bf16): cols 0..63 Q, 64..127 K, 128..191 V
    const float if0 = inv_freq_of(lo);
    const float if1 = inv_freq_of(16 + lo);
    #pragma unroll
    for (int r = 0; r < 4; ++r) {
        int orow = 16 * w + 4 * hi + r;
        float fp = (float)pos[(size_t)z * Tn + row0 + orow];
        float s0, c0, s1, c1;
        sincosf(fp * if0, &s0, &c0);
        sincosf(fp * if1, &s1, &c1);
        float qa = acc[0][r], qb = acc[2][r], qc = acc[1][r], qd = acc[3][r];
        O_lds[orow][lo]           = f2bf(qa * c0 - qb * s0);
        O_lds[orow][lo + 32]      = f2bf(qb * c0 + qa * s0);
        O_lds[orow][16 + lo]      = f2bf(qc * c1 - qd * s1);
        O_lds[orow][16 + lo + 32] = f2bf(qd * c1 + qc * s1);
        float ka = acc[4][r], kb = acc[6][r], kc = acc[5][r], kd = acc[7][r];
        O_lds[orow][64 + lo]      = f2bf(ka * c0 - kb * s0);
        O_lds[orow][64 + lo + 32] = f2bf(kb * c0 + ka * s0);
        O_lds[orow][80 + lo]      = f2bf(kc * c1 - kd * s1);
        O_lds[orow][80 + lo + 32] = f2bf(kd * c1 + kc * s1);
        O_lds[orow][128 + lo]     = f2bf(acc[8][r]);
        O_lds[orow][144 + lo]     = f2bf(acc[9][r]);
        O_lds[orow][160 + lo]     = f2bf(acc[10][r]);
        O_lds[orow][176 + lo]     = f2bf(acc[11][r]);
    }
    __syncthreads();
    #pragma unroll
    for (int p = 0; p < 2; ++p) {   // Q,K coalesced
        int task = tid + 256 * p, t = task >> 3, g = task & 7;
        *(uint4*)(Qw + ((size_t)z * Tn + row0 + t) * 64 + 8 * g) = *(uint4*)&O_lds[t][8 * g];
        *(uint4*)(Kw + ((size_t)z * Tn + row0 + t) * 64 + 8 * g) = *(uint4*)&O_lds[t][64 + 8 * g];
    }
    #pragma unroll
    for (int p = 0; p < 2; ++p) {   // V transposed -> Vt[z][d][t]
        int task = tid + 256 * p, d = task & 63, g = task >> 6;
        uint4 wv4; unsigned short* wp = (unsigned short*)&wv4;
        #pragma unroll
        for (int j = 0; j < 8; ++j) wp[j] = O_lds[8 * g + j][128 + d];
        *(uint4*)(Vt + (size_t)z * 64 * VTS + (size_t)d * VTS + row0 + 8 * g) = wv4;
    }
}

// ---------------------------------------------------------------------------
// flash_attn (MFMA): QBLK=64, KVBLK=64, 4 waves x 16-row stripes.
// S = mfma(Q,K); online softmax on accs; P via LDS; O += mfma(P,V^T).
// ---------------------------------------------------------------------------
__global__ __launch_bounds__(256) void flash_attn(
    const unsigned short* __restrict__ Qw, const unsigned short* __restrict__ Kw,
    const unsigned short* __restrict__ Vt, const int* __restrict__ act,
    unsigned short* __restrict__ At)
{
    __shared__ unsigned short K_lds[64][72];
    __shared__ unsigned short V_lds[64][72];
    __shared__ unsigned short P_lds[64][72];
    __shared__ unsigned char aK[64];
    const int z = blockIdx.y;
    const int rt = (int)gridDim.x - 1 - (int)blockIdx.x;   // longest-first
    const int row0 = rt * 64;
    const int tid = (int)threadIdx.x;
    const int w = tid >> 6, lane = tid & 63, hi = lane >> 4, lo = lane & 15;

    // Q fragments direct from global (row-major bf16)
    const unsigned short* qb = Qw + ((size_t)z * Tn + row0 + 16 * w + lo) * 64 + 8 * hi;
    bf16x8 aq0 = *(const bf16x8*)qb;
    bf16x8 aq1 = *(const bf16x8*)(qb + 32);

    bool aqv[4]; float m_[4], ls[4];
    f32x4 accO[4];
    #pragma unroll
    for (int r = 0; r < 4; ++r) {
        aqv[r] = act[(size_t)z * Tn + row0 + 16 * w + 4 * hi + r] != 0;
        m_[r] = -INFINITY; ls[r] = 0.f;
        accO[r] = (f32x4){0.f, 0.f, 0.f, 0.f};
    }

    for (int kt = 0; kt <= rt; ++kt) {
        const int j0 = kt * 64;
        __syncthreads();
        {   // stage K (row-major) and V^T tiles
            int r = tid >> 2, c = tid & 3;
            const unsigned short* s = Kw + ((size_t)z * Tn + j0 + r) * 64 + 16 * c;
            *(uint4*)&K_lds[r][16 * c]     = *(const uint4*)s;
            *(uint4*)&K_lds[r][16 * c + 8] = *(const uint4*)(s + 8);
            const unsigned short* v = Vt + (size_t)z * 64 * VTS + (size_t)r * VTS + j0 + 16 * c;
            *(uint4*)&V_lds[r][16 * c]     = *(const uint4*)v;
            *(uint4*)&V_lds[r][16 * c + 8] = *(const uint4*)(v + 8);
        }
        if (tid < 64) aK[tid] = (unsigned char)(act[(size_t)z * Tn + j0 + tid] != 0);
        __syncthreads();

        // S = Q K^T
        f32x4 s4[4];
        #pragma unroll
        for (int n = 0; n < 4; ++n) s4[n] = (f32x4){0.f, 0.f, 0.f, 0.f};
        #pragma unroll
        for (int n = 0; n < 4; ++n) {
            bf16x8 b0 = *(const bf16x8*)&K_lds[16 * n + lo][8 * hi];
            bf16x8 b1 = *(const bf16x8*)&K_lds[16 * n + lo][32 + 8 * hi];
            s4[n] = __builtin_amdgcn_mfma_f32_16x16x32_bf16(aq0, b0, s4[n], 0, 0, 0);
            s4[n] = __builtin_amdgcn_mfma_f32_16x16x32_bf16(aq1, b1, s4[n], 0, 0, 0);
        }
        unsigned char akn[4];
        #pragma unroll
        for (int n = 0; n < 4; ++n) akn[n] = aK[16 * n + lo];

        // online softmax (rows = 4 per lane, spread over 16 lanes)
        #pragma unroll
        for (int r = 0; r < 4; ++r) {
            const int rowg = row0 + 16 * w + 4 * hi + r;
            float sv[4];
            #pragma unroll
            for (int n = 0; n < 4; ++n) {
                int col = j0 + 16 * n + lo;
                sv[n] = (aqv[r] && akn[n] && col <= rowg) ? s4[n][r] * SCALE_ATTN : -INFINITY;
            }
            float mt = fmaxf(fmaxf(sv[0], sv[1]), fmaxf(sv[2], sv[3]));
            mt = fmaxf(mt, __shfl_xor(mt, 1));
            mt = fmaxf(mt, __shfl_xor(mt, 2));
            mt = fmaxf(mt, __shfl_xor(mt, 4));
            mt = fmaxf(mt, __shfl_xor(mt, 8));
            float mnew = fmaxf(m_[r], mt);
            float p[4], corr;
            if (mnew == -INFINITY) {
                p[0] = p[1] = p[2] = p[3] = 0.f; corr = 1.f;
            } else {
                corr = __expf(m_[r] - mnew);
                #pragma unroll
                for (int n = 0; n < 4; ++n) p[n] = __expf(sv[n] - mnew);
            }
            float ps = p[0] + p[1] + p[2] + p[3];
            ps += __shfl_xor(ps, 1);
            ps += __shfl_xor(ps, 2);
            ps += __shfl_xor(ps, 4);
            ps += __shfl_xor(ps, 8);
            m_[r] = mnew;
            ls[r] = ls[r] * corr + ps;
            #pragma unroll
            for (int n2 = 0; n2 < 4; ++n2) accO[n2][r] *= corr;
            int prow = 16 * w + 4 * hi + r;
            P_lds[prow][lo]      = f2bf(p[0]);
            P_lds[prow][16 + lo] = f2bf(p[1]);
            P_lds[prow][32 + lo] = f2bf(p[2]);
            P_lds[prow][48 + lo] = f2bf(p[3]);
        }
        __syncthreads();   // P visible (and LDS write->read ordered)

        // O += P V
        bf16x8 ap0 = *(const bf16x8*)&P_lds[16 * w + lo][8 * hi];
        bf16x8 ap1 = *(const bf16x8*)&P_lds[16 * w + lo][32 + 8 * hi];
        #pragma unroll
        for (int n2 = 0; n2 < 4; ++n2) {
            bf16x8 b0 = *(const bf16x8*)&V_lds[16 * n2 + lo][8 * hi];
            bf16x8 b1 = *(const bf16x8*)&V_lds[16 * n2 + lo][32 + 8 * hi];
            accO[n2] = __builtin_amdgcn_mfma_f32_16x16x32_bf16(ap0, b0, accO[n2], 0, 0, 0);
            accO[n2] = __builtin_amdgcn_mfma_f32_16x16x32_bf16(ap1, b1, accO[n2], 0, 0, 0);
        }
    }

    // finalize -> P_lds (reused) -> coalesced bf16 store
    #pragma unroll
    for (int r = 0; r < 4; ++r) {
        float inv = (aqv[r] && ls[r] > 0.f) ? 1.0f / ls[r] : 0.f;
        int prow = 16 * w + 4 * hi + r;
        P_lds[prow][lo]      = f2bf(accO[0][r] * inv);
        P_lds[prow][16 + lo] = f2bf(accO[1][r] * inv);
        P_lds[prow][32 + lo] = f2bf(accO[2][r] * inv);
        P_lds[prow][48 + lo] = f2bf(accO[3][r] * inv);
    }
    __syncthreads();
    #pragma unroll
    for (int p = 0; p < 2; ++p) {
        int task = tid + 256 * p, t = task >> 3, g = task & 7;
        *(uint4*)(At + ((size_t)z * Tn + row0 + t) * 64 + 8 * g) = *(uint4*)&P_lds[t][8 * g];
    }
}

// ---------------------------------------------------------------------------
// oproj (MFMA): out[t][d] = At[t][u] @ Wo[u][d]; 64 rows x 128 cols per block.
// B-fragments direct from L2-resident transposed bf16 ot[l][d][u].
// ---------------------------------------------------------------------------
__global__ __launch_bounds__(256) void oproj(
    const unsigned short* __restrict__ At, const unsigned short* __restrict__ ot,
    float* __restrict__ out)
{
    __shared__ unsigned short A_lds[64][72];
    const int row0 = (int)blockIdx.y * 64;
    const int c0 = (int)blockIdx.x * 128;
    const int l = (row0 >> 11) & 15;
    const int tid = (int)threadIdx.x;
    const int w = tid >> 6, lane = tid & 63, hi = lane >> 4, lo = lane & 15;
    {
        int r = tid >> 2, c = tid & 3;
        const unsigned short* s = At + ((size_t)row0 + r) * 64 + 16 * c;
        *(uint4*)&A_lds[r][16 * c]     = *(const uint4*)s;
        *(uint4*)&A_lds[r][16 * c + 8] = *(const uint4*)(s + 8);
    }
    __syncthreads();
    bf16x8 a0 = *(const bf16x8*)&A_lds[16 * w + lo][8 * hi];
    bf16x8 a1 = *(const bf16x8*)&A_lds[16 * w + lo][32 + 8 * hi];
    const unsigned short* ob = ot + (size_t)l * 65536;
    f32x4 acc[8];
    #pragma unroll
    for (int n = 0; n < 8; ++n) acc[n] = (f32x4){0.f, 0.f, 0.f, 0.f};
    #pragma unroll
    for (int n = 0; n < 8; ++n) {
        const unsigned short* bp = ob + (size_t)(c0 + 16 * n + lo) * 64;
        bf16x8 b0 = *(const bf16x8*)(bp + 8 * hi);
        bf16x8 b1 = *(const bf16x8*)(bp + 32 + 8 * hi);
        acc[n] = __builtin_amdgcn_mfma_f32_16x16x32_bf16(a0, b0, acc[n], 0, 0, 0);
        acc[n] = __builtin_amdgcn_mfma_f32_16x16x32_bf16(a1, b1, acc[n], 0, 0, 0);
    }
    #pragma unroll
    for (int n = 0; n < 8; ++n)
        #pragma unroll
        for (int r = 0; r < 4; ++r)
            out[(size_t)(row0 + 16 * w + 4 * hi + r) * 1024 + c0 + 16 * n + lo] = acc[n][r];
}

extern "C" void kernel_launch(void* const* d_in, const int* in_sizes, int n_in,
                              void* d_out, int out_size, void* d_ws, size_t ws_size,
                              hipStream_t stream) {
    const float* emb = (const float*)d_in[0];
    const int* pos = (const int*)d_in[1];
    const int* act = (const int*)d_in[2];   // int32 (proven R3->R4)
    const float* qp = (const float*)d_in[3];
    const float* kp = (const float*)d_in[4];
    const float* vp = (const float*)d_in[5];
    const float* op = (const float*)d_in[6];
    float* out = (float*)d_out;

    unsigned char* W = (unsigned char*)d_ws;
    unsigned short* qt = (unsigned short*)(W + (size_t)0);
    unsigned short* kt = (unsigned short*)(W + ((size_t)2 << 20));
    unsigned short* vt = (unsigned short*)(W + ((size_t)4 << 20));
    unsigned short* ot = (unsigned short*)(W + ((size_t)6 << 20));
    unsigned short* Qw = (unsigned short*)(W + ((size_t)8 << 20));
    unsigned short* Kw = (unsigned short*)(W + ((size_t)16 << 20));
    unsigned short* At = (unsigned short*)(W + ((size_t)24 << 20));
    unsigned short* Vt = (unsigned short*)(W + ((size_t)32 << 20));

    dim3 blk(256);
    prep_w<<<dim3(16, 16, 4), blk, 0, stream>>>(qp, kp, vp, op, qt, kt, vt, ot);
    qkv_rope<<<dim3(Tn / 64, Bn * Ln), blk, 0, stream>>>(emb, pos, qt, kt, vt, Qw, Kw, Vt);
    flash_attn<<<dim3(Tn / 64, Bn * Ln), blk, 0, stream>>>(Qw, Kw, Vt, act, At);
    oproj<<<dim3(Dn / 128, (Bn * Ln * Tn) / 64), blk, 0, stream>>>(At, ot, out);
}

// Round 12
// 682.580 us; speedup vs baseline: 2.1397x; 1.1232x over previous
//
#include <hip/hip_runtime.h>
#include <hip/hip_bf16.h>
#include <math.h>

typedef __attribute__((ext_vector_type(8))) short bf16x8;
typedef __attribute__((ext_vector_type(4))) float f32x4;

static constexpr int Bn = 2, Ln = 16, Tn = 2048, Dn = 1024, Un = 64;
static constexpr float SCALE_ATTN = 0.14232867951f; // (0.1*ln(4)+1)/sqrt(64)
static constexpr int VTS = 2080;                    // V^T ws row stride (elems)

__device__ __forceinline__ unsigned short f2bf(float x) {
    __hip_bfloat16 h = __float2bfloat16(x);
    return *reinterpret_cast<unsigned short*>(&h);
}
__device__ __forceinline__ unsigned int pk2(float a, float b) {
    return (unsigned int)f2bf(a) | ((unsigned int)f2bf(b) << 16);
}
// YaRN: low=8, high=21, denom=13 (validated R8/R11)
__device__ __forceinline__ float inv_freq_of(int d) {
    float p = powf(10000.0f, (float)d * (1.0f / 32.0f));
    float ramp = fminf(fmaxf(((float)d - 8.0f) * (1.0f / 13.0f), 0.0f), 1.0f);
    return (0.25f / p) * ramp + (1.0f / p) * (1.0f - ramp);
}

// ---------------------------------------------------------------------------
// prep_w: fp32 weights -> bf16.
// q/k/v: PANEL layout [l][kp=32][u=64][ki=32] (4KB contiguous per K-step).
// o:     [l][d=1024][u=64].
// ---------------------------------------------------------------------------
__global__ __launch_bounds__(256) void prep_w(
    const float* __restrict__ qp, const float* __restrict__ kp,
    const float* __restrict__ vp, const float* __restrict__ op,
    unsigned short* __restrict__ qt, unsigned short* __restrict__ kt,
    unsigned short* __restrict__ vt, unsigned short* __restrict__ ot)
{
    __shared__ unsigned short T[64][72];
    const int m = blockIdx.z, l = blockIdx.y, x = blockIdx.x;
    const int tid = (int)threadIdx.x;
    const float* sb = (m == 0 ? qp : m == 1 ? kp : m == 2 ? vp : op) + (size_t)l * 65536;
    unsigned short* db = (m == 0 ? qt : m == 1 ? kt : m == 2 ? vt : ot) + (size_t)l * 65536;
    #pragma unroll
    for (int p = 0; p < 4; ++p) {
        int r = (tid >> 4) + 16 * p, c4 = (tid & 15) * 4;
        size_t s = (m < 3) ? ((size_t)(64 * x + r) * 64 + c4)      // rows=k, cols=u
                           : ((size_t)r * 1024 + 64 * x + c4);     // rows=u, cols=d
        float4 v = *(const float4*)(sb + s);
        T[r][c4 + 0] = f2bf(v.x); T[r][c4 + 1] = f2bf(v.y);
        T[r][c4 + 2] = f2bf(v.z); T[r][c4 + 3] = f2bf(v.w);
    }
    __syncthreads();
    if (m < 3) {
        // panels 2x, 2x+1: dst = kp*2048 + u*32 + ki, data = T[k_local][u]
        #pragma unroll
        for (int p = 0; p < 2; ++p) {
            int task = tid + 256 * p;
            int u = task >> 3, kio = task & 7;
            uint4 wv; unsigned short* wp = (unsigned short*)&wv;
            #pragma unroll
            for (int j = 0; j < 8; ++j) wp[j] = T[8 * kio + j][u];
            size_t d = (size_t)(2 * x + (kio >> 2)) * 2048 + (size_t)u * 32 + 8 * (kio & 3);
            *(uint4*)(db + d) = wv;
        }
    } else {
        #pragma unroll
        for (int p = 0; p < 2; ++p) {
            int task = tid + 256 * p;
            int c = task >> 3, g = task & 7;
            uint4 wv; unsigned short* wp = (unsigned short*)&wv;
            #pragma unroll
            for (int j = 0; j < 8; ++j) wp[j] = T[8 * g + j][c];
            size_t d = (size_t)(64 * x + c) * 64 + 8 * g;          // ot[d][u]
            *(uint4*)(db + d) = wv;
        }
    }
}

// ---------------------------------------------------------------------------
// qkv_rope v2 (MFMA, double-buffered): per block one (b,l), 64 rows x 192
// cols, K=1024. Per K-step: coalesced staging of A-tile (f32->bf16) and the
// three 4KB weight panels into LDS[2]; next-step loads issued during MFMA.
// RoPE on fp32 accumulators; epilogue LDS overlaid on staging buffers.
// ---------------------------------------------------------------------------
__global__ __launch_bounds__(256) void qkv_rope(
    const float* __restrict__ emb, const int* __restrict__ pos,
    const unsigned short* __restrict__ qt, const unsigned short* __restrict__ kt,
    const unsigned short* __restrict__ vt,
    unsigned short* __restrict__ Qw, unsigned short* __restrict__ Kw,
    unsigned short* __restrict__ Vt)
{
    __shared__ union {
        struct {
            unsigned short A[2][64][40];     // 10240 B (rows 80B, 16B-aligned)
            unsigned short W[2][3][64][40];  // 30720 B
        } st;
        unsigned short O[64][200];           // 25600 B (epilogue overlay)
    } sm;

    const int z = blockIdx.y, l = z & 15, row0 = blockIdx.x * 64;
    const int tid = (int)threadIdx.x;
    const int w = tid >> 6, lane = tid & 63, hi = lane >> 4, lo = lane & 15;

    f32x4 acc[12];
    #pragma unroll
    for (int i = 0; i < 12; ++i) acc[i] = (f32x4){0.f, 0.f, 0.f, 0.f};

    const float* embB = emb + ((size_t)z * Tn + row0) * Dn;
    const unsigned short* wb[3] = {qt + (size_t)l * 65536, kt + (size_t)l * 65536,
                                   vt + (size_t)l * 65536};

    // prefetch registers
    float4 pa0, pa1; uint4 pw0, pw1, pw2;
    const int ar = tid >> 2, ac8 = (tid & 3) * 8;   // A: 8 floats/thread
    #define LDR(s) do {                                                        \
        const float* _s = embB + (size_t)ar * Dn + (s) * 32 + ac8;             \
        pa0 = *(const float4*)_s; pa1 = *(const float4*)(_s + 4);              \
        size_t _w = (size_t)(s) * 2048 + (size_t)tid * 8;                      \
        pw0 = *(const uint4*)(wb[0] + _w);                                     \
        pw1 = *(const uint4*)(wb[1] + _w);                                     \
        pw2 = *(const uint4*)(wb[2] + _w);                                     \
    } while (0)
    #define STR(buf) do {                                                     \
        uint4 _u = {pk2(pa0.x, pa0.y), pk2(pa0.z, pa0.w),                      \
                    pk2(pa1.x, pa1.y), pk2(pa1.z, pa1.w)};                     \
        *(uint4*)&sm.st.A[buf][ar][ac8] = _u;                                  \
        *(uint4*)&sm.st.W[buf][0][tid >> 2][(tid & 3) * 8] = pw0;              \
        *(uint4*)&sm.st.W[buf][1][tid >> 2][(tid & 3) * 8] = pw1;              \
        *(uint4*)&sm.st.W[buf][2][tid >> 2][(tid & 3) * 8] = pw2;              \
    } while (0)

    LDR(0);
    STR(0);
    __syncthreads();
    for (int s = 0; s < 32; ++s) {
        const int cur = s & 1;
        if (s + 1 < 32) LDR(s + 1);          // issue next-step global loads
        bf16x8 a = *(const bf16x8*)&sm.st.A[cur][16 * w + lo][8 * hi];
        #pragma unroll
        for (int n = 0; n < 12; ++n) {
            bf16x8 b = *(const bf16x8*)&sm.st.W[cur][n >> 2][16 * (n & 3) + lo][8 * hi];
            acc[n] = __builtin_amdgcn_mfma_f32_16x16x32_bf16(a, b, acc[n], 0, 0, 0);
        }
        __syncthreads();                     // done reading buf cur
        if (s + 1 < 32) {
            STR(cur ^ 1);
            __syncthreads();                 // buf cur^1 ready
        }
    }
    #undef LDR
    #undef STR

    // RoPE epilogue -> sm.O (bf16): cols 0..63 Q, 64..127 K, 128..191 V
    const float if0 = inv_freq_of(lo);
    const float if1 = inv_freq_of(16 + lo);
    #pragma unroll
    for (int r = 0; r < 4; ++r) {
        int orow = 16 * w + 4 * hi + r;
        float fp = (float)pos[(size_t)z * Tn + row0 + orow];
        float s0, c0, s1, c1;
        sincosf(fp * if0, &s0, &c0);
        sincosf(fp * if1, &s1, &c1);
        float qa = acc[0][r], qb = acc[2][r], qc = acc[1][r], qd = acc[3][r];
        sm.O[orow][lo]           = f2bf(qa * c0 - qb * s0);
        sm.O[orow][lo + 32]      = f2bf(qb * c0 + qa * s0);
        sm.O[orow][16 + lo]      = f2bf(qc * c1 - qd * s1);
        sm.O[orow][16 + lo + 32] = f2bf(qd * c1 + qc * s1);
        float ka = acc[4][r], kb = acc[6][r], kc = acc[5][r], kd = acc[7][r];
        sm.O[orow][64 + lo]      = f2bf(ka * c0 - kb * s0);
        sm.O[orow][64 + lo + 32] = f2bf(kb * c0 + ka * s0);
        sm.O[orow][80 + lo]      = f2bf(kc * c1 - kd * s1);
        sm.O[orow][80 + lo + 32] = f2bf(kd * c1 + kc * s1);
        sm.O[orow][128 + lo]     = f2bf(acc[8][r]);
        sm.O[orow][144 + lo]     = f2bf(acc[9][r]);
        sm.O[orow][160 + lo]     = f2bf(acc[10][r]);
        sm.O[orow][176 + lo]     = f2bf(acc[11][r]);
    }
    __syncthreads();
    #pragma unroll
    for (int p = 0; p < 2; ++p) {   // Q,K coalesced
        int task = tid + 256 * p, t = task >> 3, g = task & 7;
        *(uint4*)(Qw + ((size_t)z * Tn + row0 + t) * 64 + 8 * g) = *(uint4*)&sm.O[t][8 * g];
        *(uint4*)(Kw + ((size_t)z * Tn + row0 + t) * 64 + 8 * g) = *(uint4*)&sm.O[t][64 + 8 * g];
    }
    #pragma unroll
    for (int p = 0; p < 2; ++p) {   // V transposed -> Vt[z][d][t]
        int task = tid + 256 * p, d = task & 63, g = task >> 6;
        uint4 wv4; unsigned short* wp = (unsigned short*)&wv4;
        #pragma unroll
        for (int j = 0; j < 8; ++j) wp[j] = sm.O[8 * g + j][128 + d];
        *(uint4*)(Vt + (size_t)z * 64 * VTS + (size_t)d * VTS + row0 + 8 * g) = wv4;
    }
}

// ---------------------------------------------------------------------------
// flash_attn (MFMA): QBLK=64, KVBLK=64, 4 waves x 16-row stripes.
// S = mfma(Q,K); online softmax on accs; P via LDS; O += mfma(P,V^T).
// ---------------------------------------------------------------------------
__global__ __launch_bounds__(256) void flash_attn(
    const unsigned short* __restrict__ Qw, const unsigned short* __restrict__ Kw,
    const unsigned short* __restrict__ Vt, const int* __restrict__ act,
    unsigned short* __restrict__ At)
{
    __shared__ unsigned short K_lds[64][72];
    __shared__ unsigned short V_lds[64][72];
    __shared__ unsigned short P_lds[64][72];
    __shared__ unsigned char aK[64];
    const int z = blockIdx.y;
    const int rt = (int)gridDim.x - 1 - (int)blockIdx.x;   // longest-first
    const int row0 = rt * 64;
    const int tid = (int)threadIdx.x;
    const int w = tid >> 6, lane = tid & 63, hi = lane >> 4, lo = lane & 15;

    // Q fragments direct from global (row-major bf16)
    const unsigned short* qb = Qw + ((size_t)z * Tn + row0 + 16 * w + lo) * 64 + 8 * hi;
    bf16x8 aq0 = *(const bf16x8*)qb;
    bf16x8 aq1 = *(const bf16x8*)(qb + 32);

    bool aqv[4]; float m_[4], ls[4];
    f32x4 accO[4];
    #pragma unroll
    for (int r = 0; r < 4; ++r) {
        aqv[r] = act[(size_t)z * Tn + row0 + 16 * w + 4 * hi + r] != 0;
        m_[r] = -INFINITY; ls[r] = 0.f;
        accO[r] = (f32x4){0.f, 0.f, 0.f, 0.f};
    }

    for (int kt = 0; kt <= rt; ++kt) {
        const int j0 = kt * 64;
        __syncthreads();
        {   // stage K (row-major) and V^T tiles
            int r = tid >> 2, c = tid & 3;
            const unsigned short* s = Kw + ((size_t)z * Tn + j0 + r) * 64 + 16 * c;
            *(uint4*)&K_lds[r][16 * c]     = *(const uint4*)s;
            *(uint4*)&K_lds[r][16 * c + 8] = *(const uint4*)(s + 8);
            const unsigned short* v = Vt + (size_t)z * 64 * VTS + (size_t)r * VTS + j0 + 16 * c;
            *(uint4*)&V_lds[r][16 * c]     = *(const uint4*)v;
            *(uint4*)&V_lds[r][16 * c + 8] = *(const uint4*)(v + 8);
        }
        if (tid < 64) aK[tid] = (unsigned char)(act[(size_t)z * Tn + j0 + tid] != 0);
        __syncthreads();

        // S = Q K^T
        f32x4 s4[4];
        #pragma unroll
        for (int n = 0; n < 4; ++n) s4[n] = (f32x4){0.f, 0.f, 0.f, 0.f};
        #pragma unroll
        for (int n = 0; n < 4; ++n) {
            bf16x8 b0 = *(const bf16x8*)&K_lds[16 * n + lo][8 * hi];
            bf16x8 b1 = *(const bf16x8*)&K_lds[16 * n + lo][32 + 8 * hi];
            s4[n] = __builtin_amdgcn_mfma_f32_16x16x32_bf16(aq0, b0, s4[n], 0, 0, 0);
            s4[n] = __builtin_amdgcn_mfma_f32_16x16x32_bf16(aq1, b1, s4[n], 0, 0, 0);
        }
        unsigned char akn[4];
        #pragma unroll
        for (int n = 0; n < 4; ++n) akn[n] = aK[16 * n + lo];

        // online softmax (rows = 4 per lane, spread over 16 lanes)
        #pragma unroll
        for (int r = 0; r < 4; ++r) {
            const int rowg = row0 + 16 * w + 4 * hi + r;
            float sv[4];
            #pragma unroll
            for (int n = 0; n < 4; ++n) {
                int col = j0 + 16 * n + lo;
                sv[n] = (aqv[r] && akn[n] && col <= rowg) ? s4[n][r] * SCALE_ATTN : -INFINITY;
            }
            float mt = fmaxf(fmaxf(sv[0], sv[1]), fmaxf(sv[2], sv[3]));
            mt = fmaxf(mt, __shfl_xor(mt, 1));
            mt = fmaxf(mt, __shfl_xor(mt, 2));
            mt = fmaxf(mt, __shfl_xor(mt, 4));
            mt = fmaxf(mt, __shfl_xor(mt, 8));
            float mnew = fmaxf(m_[r], mt);
            float p[4], corr;
            if (mnew == -INFINITY) {
                p[0] = p[1] = p[2] = p[3] = 0.f; corr = 1.f;
            } else {
                corr = __expf(m_[r] - mnew);
                #pragma unroll
                for (int n = 0; n < 4; ++n) p[n] = __expf(sv[n] - mnew);
            }
            float ps = p[0] + p[1] + p[2] + p[3];
            ps += __shfl_xor(ps, 1);
            ps += __shfl_xor(ps, 2);
            ps += __shfl_xor(ps, 4);
            ps += __shfl_xor(ps, 8);
            m_[r] = mnew;
            ls[r] = ls[r] * corr + ps;
            #pragma unroll
            for (int n2 = 0; n2 < 4; ++n2) accO[n2][r] *= corr;
            int prow = 16 * w + 4 * hi + r;
            P_lds[prow][lo]      = f2bf(p[0]);
            P_lds[prow][16 + lo] = f2bf(p[1]);
            P_lds[prow][32 + lo] = f2bf(p[2]);
            P_lds[prow][48 + lo] = f2bf(p[3]);
        }
        __syncthreads();   // P visible (and LDS write->read ordered)

        // O += P V
        bf16x8 ap0 = *(const bf16x8*)&P_lds[16 * w + lo][8 * hi];
        bf16x8 ap1 = *(const bf16x8*)&P_lds[16 * w + lo][32 + 8 * hi];
        #pragma unroll
        for (int n2 = 0; n2 < 4; ++n2) {
            bf16x8 b0 = *(const bf16x8*)&V_lds[16 * n2 + lo][8 * hi];
            bf16x8 b1 = *(const bf16x8*)&V_lds[16 * n2 + lo][32 + 8 * hi];
            accO[n2] = __builtin_amdgcn_mfma_f32_16x16x32_bf16(ap0, b0, accO[n2], 0, 0, 0);
            accO[n2] = __builtin_amdgcn_mfma_f32_16x16x32_bf16(ap1, b1, accO[n2], 0, 0, 0);
        }
    }

    // finalize -> P_lds (reused) -> coalesced bf16 store
    #pragma unroll
    for (int r = 0; r < 4; ++r) {
        float inv = (aqv[r] && ls[r] > 0.f) ? 1.0f / ls[r] : 0.f;
        int prow = 16 * w + 4 * hi + r;
        P_lds[prow][lo]      = f2bf(accO[0][r] * inv);
        P_lds[prow][16 + lo] = f2bf(accO[1][r] * inv);
        P_lds[prow][32 + lo] = f2bf(accO[2][r] * inv);
        P_lds[prow][48 + lo] = f2bf(accO[3][r] * inv);
    }
    __syncthreads();
    #pragma unroll
    for (int p = 0; p < 2; ++p) {
        int task = tid + 256 * p, t = task >> 3, g = task & 7;
        *(uint4*)(At + ((size_t)z * Tn + row0 + t) * 64 + 8 * g) = *(uint4*)&P_lds[t][8 * g];
    }
}

// ---------------------------------------------------------------------------
// oproj (MFMA): out[t][d] = At[t][u] @ Wo[u][d]; 64 rows x 128 cols per block.
// B-fragments direct from L2-resident transposed bf16 ot[l][d][u].
// ---------------------------------------------------------------------------
__global__ __launch_bounds__(256) void oproj(
    const unsigned short* __restrict__ At, const unsigned short* __restrict__ ot,
    float* __restrict__ out)
{
    __shared__ unsigned short A_lds[64][72];
    const int row0 = (int)blockIdx.y * 64;
    const int c0 = (int)blockIdx.x * 128;
    const int l = (row0 >> 11) & 15;
    const int tid = (int)threadIdx.x;
    const int w = tid >> 6, lane = tid & 63, hi = lane >> 4, lo = lane & 15;
    {
        int r = tid >> 2, c = tid & 3;
        const unsigned short* s = At + ((size_t)row0 + r) * 64 + 16 * c;
        *(uint4*)&A_lds[r][16 * c]     = *(const uint4*)s;
        *(uint4*)&A_lds[r][16 * c + 8] = *(const uint4*)(s + 8);
    }
    __syncthreads();
    bf16x8 a0 = *(const bf16x8*)&A_lds[16 * w + lo][8 * hi];
    bf16x8 a1 = *(const bf16x8*)&A_lds[16 * w + lo][32 + 8 * hi];
    const unsigned short* ob = ot + (size_t)l * 65536;
    f32x4 acc[8];
    #pragma unroll
    for (int n = 0; n < 8; ++n) acc[n] = (f32x4){0.f, 0.f, 0.f, 0.f};
    #pragma unroll
    for (int n = 0; n < 8; ++n) {
        const unsigned short* bp = ob + (size_t)(c0 + 16 * n + lo) * 64;
        bf16x8 b0 = *(const bf16x8*)(bp + 8 * hi);
        bf16x8 b1 = *(const bf16x8*)(bp + 32 + 8 * hi);
        acc[n] = __builtin_amdgcn_mfma_f32_16x16x32_bf16(a0, b0, acc[n], 0, 0, 0);
        acc[n] = __builtin_amdgcn_mfma_f32_16x16x32_bf16(a1, b1, acc[n], 0, 0, 0);
    }
    #pragma unroll
    for (int n = 0; n < 8; ++n)
        #pragma unroll
        for (int r = 0; r < 4; ++r)
            out[(size_t)(row0 + 16 * w + 4 * hi + r) * 1024 + c0 + 16 * n + lo] = acc[n][r];
}

extern "C" void kernel_launch(void* const* d_in, const int* in_sizes, int n_in,
                              void* d_out, int out_size, void* d_ws, size_t ws_size,
                              hipStream_t stream) {
    const float* emb = (const float*)d_in[0];
    const int* pos = (const int*)d_in[1];
    const int* act = (const int*)d_in[2];   // int32 (proven R3->R4)
    const float* qp = (const float*)d_in[3];
    const float* kp = (const float*)d_in[4];
    const float* vp = (const float*)d_in[5];
    const float* op = (const float*)d_in[6];
    float* out = (float*)d_out;

    unsigned char* W = (unsigned char*)d_ws;
    unsigned short* qt = (unsigned short*)(W + (size_t)0);
    unsigned short* kt = (unsigned short*)(W + ((size_t)2 << 20));
    unsigned short* vt = (unsigned short*)(W + ((size_t)4 << 20));
    unsigned short* ot = (unsigned short*)(W + ((size_t)6 << 20));
    unsigned short* Qw = (unsigned short*)(W + ((size_t)8 << 20));
    unsigned short* Kw = (unsigned short*)(W + ((size_t)16 << 20));
    unsigned short* At = (unsigned short*)(W + ((size_t)24 << 20));
    unsigned short* Vt = (unsigned short*)(W + ((size_t)32 << 20));

    dim3 blk(256);
    prep_w<<<dim3(16, 16, 4), blk, 0, stream>>>(qp, kp, vp, op, qt, kt, vt, ot);
    qkv_rope<<<dim3(Tn / 64, Bn * Ln), blk, 0, stream>>>(emb, pos, qt, kt, vt, Qw, Kw, Vt);
    flash_attn<<<dim3(Tn / 64, Bn * Ln), blk, 0, stream>>>(Qw, Kw, Vt, act, At);
    oproj<<<dim3(Dn / 128, (Bn * Ln * Tn) / 64), blk, 0, stream>>>(At, ot, out);
}